// Round 6
// baseline (4564.054 us; speedup 1.0000x reference)
//
#include <hip/hip_runtime.h>

// ============================================================================
// PointNet++ (8 batches, N=4096) forward on MI355X — full pipeline, fp32.
// Stages: FPS -> ball query (exact K-NN-in-ball via radix select) ->
//         per-center MLP+maxpool (x2) -> global MLP+max -> head MLP.
// Round 6: FPS — 512 thr (2 waves/SIMD), packed-f32 math, xyz carried through
// the reduction, and NO global stores inside the barrier loop (results
// accumulate in LDS; the pre-barrier drain is lgkmcnt not vmcnt).
// ============================================================================

constexpr int NBATCH = 8;

typedef float v2f __attribute__((ext_vector_type(2)));

// ---- DPP wave64 reduction helpers -----------------------------------------
template<int CTRL>
__device__ __forceinline__ float dpp_max_step(float v) {
  int o = __builtin_amdgcn_update_dpp(__float_as_int(v), __float_as_int(v),
                                      CTRL, 0xf, 0xf, false);  // invalid -> old(=v)
  return fmaxf(v, __int_as_float(o));
}
// full-wave max; result valid in lane 63; readlane(63) broadcasts
__device__ __forceinline__ float wave_max_bcast(float v) {
  v = dpp_max_step<0x111>(v);  // row_shr:1
  v = dpp_max_step<0x112>(v);  // row_shr:2
  v = dpp_max_step<0x114>(v);  // row_shr:4
  v = dpp_max_step<0x118>(v);  // row_shr:8
  v = dpp_max_step<0x142>(v);  // row_bcast:15
  v = dpp_max_step<0x143>(v);  // row_bcast:31
  return __int_as_float(__builtin_amdgcn_readlane(__float_as_int(v), 63));
}
template<int CTRL>
__device__ __forceinline__ int dpp_add_step(int v) {
  int o = __builtin_amdgcn_update_dpp(0, v, CTRL, 0xf, 0xf, true);  // invalid -> 0
  return v + o;
}
__device__ __forceinline__ int wave_sum_bcast(int v) {
  v = dpp_add_step<0x111>(v);
  v = dpp_add_step<0x112>(v);
  v = dpp_add_step<0x114>(v);
  v = dpp_add_step<0x118>(v);
  v = dpp_add_step<0x142>(v);
  v = dpp_add_step<0x143>(v);
  return __builtin_amdgcn_readlane(v, 63);
}

// ---------------------------------------------------------------------------
// Farthest point sampling: one block per batch cloud, NTH threads.
// idx[0]=0; idx[s]=argmax(min_d); ties -> lowest index (== jnp.argmax).
// Points in registers (v2f pairs, packed-f32 ALU). Per step: packed dist+min
// update, per-lane argmax (lane-major layout -> scan order == index order),
// DPP wave max, ballot lowest-lane, winner xyz readlane'd; per-wave
// {key,xyz} -> LDS; ONE barrier; NW-way merge gives next center from LDS.
// idx/centers accumulate in LDS; single coalesced global dump at the end
// (no vmcnt drain before the per-step barrier).
// ---------------------------------------------------------------------------
template<int NPTS, int NTH, int NSAMP>
__global__ __launch_bounds__(NTH) void fps_kernel(const float* __restrict__ pos,
    int* __restrict__ idx_out, float* __restrict__ c_out) {
#pragma clang fp contract(off)
  constexpr int PT = NPTS / NTH;       // points per thread
  constexpr int NP = PT / 2;           // v2f pairs per thread
  constexpr int NW = NTH / 64;
  const int b = blockIdx.x;
  const float* p = pos + (size_t)b * NPTS * 3;
  __shared__ unsigned long long skey[2][NW];
  __shared__ float sxyz[2][NW][3];
  __shared__ int   sidx[NSAMP];
  __shared__ float scb[NSAMP * 3];
  const int t = threadIdx.x, lane = t & 63, w = t >> 6;
  v2f px[NP], py[NP], pz[NP], md[NP];
#pragma unroll
  for (int k = 0; k < NP; k++) {
    int j = t * PT + 2 * k;
    px[k] = (v2f){p[j * 3 + 0], p[j * 3 + 3]};
    py[k] = (v2f){p[j * 3 + 1], p[j * 3 + 4]};
    pz[k] = (v2f){p[j * 3 + 2], p[j * 3 + 5]};
    md[k] = (v2f){__builtin_inff(), __builtin_inff()};
  }
  float cx = p[0], cy = p[1], cz = p[2];   // first center = point 0
  int cur = 0;
  for (int s = 0;; ++s) {
    if (t == 0) {
      sidx[s] = cur;
      scb[s * 3 + 0] = cx; scb[s * 3 + 1] = cy; scb[s * 3 + 2] = cz;
    }
    if (s == NSAMP - 1) break;
    float bv = -__builtin_inff(); int bi = 0;
    v2f cxv = {cx, cx}, cyv = {cy, cy}, czv = {cz, cz};
#pragma unroll
    for (int k = 0; k < NP; k++) {
      v2f dx = px[k] - cxv, dy = py[k] - cyv, dz = pz[k] - czv;
      v2f d = (dx * dx + dy * dy) + dz * dz;   // contract off: match XLA order
      v2f m;
      m.x = fminf(md[k].x, d.x); m.y = fminf(md[k].y, d.y);
      md[k] = m;
      if (m.x > bv) { bv = m.x; bi = 2 * k; }      // strict >: first-index ties
      if (m.y > bv) { bv = m.y; bi = 2 * k + 1; }
    }
    // wave max (value only), index via ballot (lane-major -> lowest lane wins)
    float wmax = wave_max_bcast(bv);
    unsigned long long ball = __ballot(bv == wmax);
    int fl = __ffsll((long long)ball) - 1;
    int ib = __builtin_amdgcn_readlane(bi, fl);     // wave-uniform slot
    int gidx = ((w << 6) + fl) * PT + ib;
    // select slot ib's xyz (uniform index -> small cndmask tree), lane fl's copy
    int kk = ib >> 1;
    v2f sx = px[0], sy = py[0], sz = pz[0];
#pragma unroll
    for (int k = 1; k < NP; k++)
      if (kk == k) { sx = px[k]; sy = py[k]; sz = pz[k]; }
    float wx = (ib & 1) ? sx.y : sx.x;
    float wy = (ib & 1) ? sy.y : sy.x;
    float wz = (ib & 1) ? sz.y : sz.x;
    wx = __int_as_float(__builtin_amdgcn_readlane(__float_as_int(wx), fl));
    wy = __int_as_float(__builtin_amdgcn_readlane(__float_as_int(wy), fl));
    wz = __int_as_float(__builtin_amdgcn_readlane(__float_as_int(wz), fl));
    if (lane == 0) {
      skey[s & 1][w] = (((unsigned long long)(unsigned)__float_as_int(wmax)) << 32)
                       | (unsigned)(~gidx);
      sxyz[s & 1][w][0] = wx; sxyz[s & 1][w][1] = wy; sxyz[s & 1][w][2] = wz;
    }
    __syncthreads();
    unsigned long long best = skey[s & 1][0];
    float nx = sxyz[s & 1][0][0], ny = sxyz[s & 1][0][1], nz = sxyz[s & 1][0][2];
#pragma unroll
    for (int q = 1; q < NW; q++) {
      unsigned long long k2 = skey[s & 1][q];
      bool gt = k2 > best;                          // max d-bits, ties -> min gidx
      best = gt ? k2 : best;
      nx = gt ? sxyz[s & 1][q][0] : nx;
      ny = gt ? sxyz[s & 1][q][1] : ny;
      nz = gt ? sxyz[s & 1][q][2] : nz;
    }
    cur = (int)(~(unsigned)best);
    cx = nx; cy = ny; cz = nz;                      // next center from registers
  }
  __syncthreads();
  // coalesced dump of accumulated results
  int* idxb = idx_out + (size_t)b * NSAMP;
  float* cb = c_out + (size_t)b * NSAMP * 3;
  for (int i = t; i < NSAMP; i += NTH) idxb[i] = sidx[i];
  for (int i = t; i < NSAMP * 3; i += NTH) cb[i] = scb[i];
}

// ---------------------------------------------------------------------------
// Ball query + exact 64 nearest within radius. One wave per center.
// Candidates compacted into per-wave LDS list; if >64, radix-select on the
// f32 distance bits finds the 64th-smallest; ties at threshold resolved by
// smallest point index (== lax.top_k tie semantics). Invalid slots -> idx 0.
// ---------------------------------------------------------------------------
template<int NPTS, int SPB>
__global__ __launch_bounds__(256) void ballquery_kernel(const float* __restrict__ pts,
    const float* __restrict__ ctr, float rr,
    int* __restrict__ nbr, int* __restrict__ cnt_out) {
#pragma clang fp contract(off)
  const int gw = (blockIdx.x << 2) + (threadIdx.x >> 6);
  const int lane = threadIdx.x & 63;
  const int b = gw / SPB;
  __shared__ unsigned long long list_[4][1024];
  unsigned long long* list = list_[threadIdx.x >> 6];
  const float* p = pts + (size_t)b * NPTS * 3;
  const float* c = ctr + (size_t)gw * 3;
  const float cx = c[0], cy = c[1], cz = c[2];
  const unsigned long long lmask = (1ull << lane) - 1ull;
  int cnt = 0;
  for (int j0 = 0; j0 < NPTS; j0 += 64) {
    int j = j0 + lane;
    float dx = p[j * 3 + 0] - cx, dy = p[j * 3 + 1] - cy, dz = p[j * 3 + 2] - cz;
    float d = (dx * dx + dy * dy) + dz * dz;
    bool in = (d <= rr);
    unsigned long long bal = __ballot(in);
    int pos = cnt + __popcll(bal & lmask);
    if (in && pos < 1024)
      list[pos] = (((unsigned long long)__float_as_uint(d)) << 32) | (unsigned)j;
    cnt += __popcll(bal);
  }
  if (cnt > 1024) cnt = 1024;
  __syncthreads();
  int* nbrp = nbr + (size_t)gw * 64;
  const int nr = (cnt + 63) >> 6;
  unsigned long long key[16];
#pragma unroll
  for (int r = 0; r < 16; r++) {
    int slot = r * 64 + lane;
    key[r] = (r < nr && slot < cnt) ? list[slot] : ~0ull;
  }
  if (cnt <= 64) {
    nbrp[lane] = (lane < cnt) ? (int)(unsigned)key[0] : 0;
    if (lane == 0) cnt_out[gw] = cnt;
    return;
  }
  // radix select on d2 bits (d2 in [0, rr] < 2.0 -> bits 31:30 are 0)
  unsigned pref = 0; int cbase = 0;
  for (int bit = 29; bit >= 0; --bit) {
    int cc = 0;
#pragma unroll
    for (int r = 0; r < 16; r++) if (r < nr) {
      unsigned db = (unsigned)(key[r] >> 32);
      cc += ((db >> bit) == (pref >> bit)) ? 1 : 0;
    }
    cc = wave_sum_bcast(cc);
    if (cbase + cc < 64) { cbase += cc; pref |= (1u << bit); }
  }
  // emit all keys with d-bits strictly below threshold
  int base = 0;
#pragma unroll
  for (int r = 0; r < 16; r++) if (r < nr) {
    unsigned db = (unsigned)(key[r] >> 32);
    bool sel = db < pref;
    unsigned long long m = __ballot(sel);
    if (sel) nbrp[base + __popcll(m & lmask)] = (int)(unsigned)key[r];
    base += __popcll(m);
  }
  // ties at threshold: take smallest indices until 64 total
  int need = 64 - base;
  for (int t2 = 0; t2 < need; ++t2) {
    unsigned besti = 0xffffffffu;
#pragma unroll
    for (int r = 0; r < 16; r++) if (r < nr) {
      if ((unsigned)(key[r] >> 32) == pref) {
        unsigned v = (unsigned)key[r];
        besti = v < besti ? v : besti;
      }
    }
#pragma unroll
    for (int off = 32; off; off >>= 1) {
      unsigned o = __shfl_xor(besti, off, 64);
      besti = o < besti ? o : besti;
    }
    unsigned long long wk = (((unsigned long long)pref) << 32) | besti;
#pragma unroll
    for (int r = 0; r < 16; r++) if (r < nr && key[r] == wk) key[r] = ~0ull;
    if (lane == 0) nbrp[base + t2] = (int)besti;
  }
  if (lane == 0) cnt_out[gw] = 64;
}

// ---------------------------------------------------------------------------
// SA1 layer-1 split: q[j] = [x_j,pos_j] @ W1  (per point), t[s] = b1 - c_s@W1[3:6]
// ---------------------------------------------------------------------------
__global__ __launch_bounds__(256) void q1_kernel(const float* __restrict__ x,
    const float* __restrict__ pos, const float* __restrict__ w, float* __restrict__ q) {
  int gw = (blockIdx.x << 2) + (threadIdx.x >> 6), lane = threadIdx.x & 63;
  const float* xr = x + (size_t)gw * 3; const float* pr = pos + (size_t)gw * 3;
  float a = 0.f;
#pragma unroll
  for (int m = 0; m < 3; m++) a = fmaf(xr[m], w[m * 64 + lane], a);
#pragma unroll
  for (int m = 0; m < 3; m++) a = fmaf(pr[m], w[(3 + m) * 64 + lane], a);
  q[(size_t)gw * 64 + lane] = a;
}

__global__ __launch_bounds__(256) void t1_kernel(const float* __restrict__ c1,
    const float* __restrict__ w, const float* __restrict__ b1, float* __restrict__ t) {
  int gw = (blockIdx.x << 2) + (threadIdx.x >> 6), lane = threadIdx.x & 63;
  const float* cr = c1 + (size_t)gw * 3;
  float a = b1[lane];
#pragma unroll
  for (int m = 0; m < 3; m++) a = fmaf(-cr[m], w[(3 + m) * 64 + lane], a);
  t[(size_t)gw * 64 + lane] = a;
}

// SA2 layer-1 split: q2[j] = [x1_j,p1_j] @ W1 (131->128), t2[s] = b1 - c_s@W1[128:131]
__global__ __launch_bounds__(256) void q2_kernel(const float* __restrict__ x1,
    const float* __restrict__ p1, const float* __restrict__ w, float* __restrict__ q2) {
  int gw = (blockIdx.x << 2) + (threadIdx.x >> 6), lane = threadIdx.x & 63;
  const float* xr = x1 + (size_t)gw * 128; const float* pr = p1 + (size_t)gw * 3;
  float a0 = 0.f, a1 = 0.f;
#pragma unroll 8
  for (int m = 0; m < 128; m++) {
    float v = xr[m];
    a0 = fmaf(v, w[m * 128 + lane], a0);
    a1 = fmaf(v, w[m * 128 + 64 + lane], a1);
  }
#pragma unroll
  for (int m = 0; m < 3; m++) {
    float v = pr[m];
    a0 = fmaf(v, w[(128 + m) * 128 + lane], a0);
    a1 = fmaf(v, w[(128 + m) * 128 + 64 + lane], a1);
  }
  q2[(size_t)gw * 128 + lane] = a0;
  q2[(size_t)gw * 128 + 64 + lane] = a1;
}

__global__ __launch_bounds__(256) void t2_kernel(const float* __restrict__ c2,
    const float* __restrict__ w, const float* __restrict__ b1, float* __restrict__ t) {
  int gw = (blockIdx.x << 2) + (threadIdx.x >> 6), lane = threadIdx.x & 63;
  const float* cr = c2 + (size_t)gw * 3;
  float a0 = b1[lane], a1 = b1[64 + lane];
#pragma unroll
  for (int m = 0; m < 3; m++) {
    a0 = fmaf(-cr[m], w[(128 + m) * 128 + lane], a0);
    a1 = fmaf(-cr[m], w[(128 + m) * 128 + 64 + lane], a1);
  }
  t[(size_t)gw * 128 + lane] = a0;
  t[(size_t)gw * 128 + 64 + lane] = a1;
}

// ---------------------------------------------------------------------------
// Per-center: h1[k] = relu(q[nbr_k] + t_s); h2 = h1 @ W2 + b2; out = max_k h2.
// One wave per center; lane = neighbor k; W2/b2/t via uniform (scalar) loads.
// ---------------------------------------------------------------------------
template<int CIN, int COUT, int OSTR, int NPB, int SPB>
__global__ __launch_bounds__(256) void sa_pool(const float* __restrict__ q,
    const float* __restrict__ t, const int* __restrict__ nbr, const int* __restrict__ cnt,
    const float* __restrict__ w2, const float* __restrict__ b2, float* __restrict__ out) {
  int gw = (blockIdx.x << 2) + (threadIdx.x >> 6), lane = threadIdx.x & 63;
  int b = gw / SPB;
  int nk = nbr[(size_t)gw * 64 + lane];
  int c = cnt[gw];
  const float* qr = q + ((size_t)b * NPB + nk) * CIN;
  const float* tr = t + (size_t)gw * CIN;
  float h[CIN];
#pragma unroll
  for (int i = 0; i < CIN; i += 4) {
    float4 v = *(const float4*)(qr + i);
    h[i]     = fmaxf(v.x + tr[i], 0.f);
    h[i + 1] = fmaxf(v.y + tr[i + 1], 0.f);
    h[i + 2] = fmaxf(v.z + tr[i + 2], 0.f);
    h[i + 3] = fmaxf(v.w + tr[i + 3], 0.f);
  }
  bool valid = lane < c;
  float* op = out + (size_t)gw * OSTR;
#pragma unroll 1
  for (int nc = 0; nc < COUT; nc += 16) {
    float acc[16];
#pragma unroll
    for (int u = 0; u < 16; u++) acc[u] = b2[nc + u];
#pragma unroll
    for (int i = 0; i < CIN; i++) {
      const float* wr = w2 + (size_t)i * COUT + nc;
#pragma unroll
      for (int u = 0; u < 16; u++) acc[u] = fmaf(h[i], wr[u], acc[u]);
    }
#pragma unroll
    for (int u = 0; u < 16; u++) {
      float v = valid ? acc[u] : -__builtin_inff();
#pragma unroll
      for (int off = 32; off; off >>= 1) v = fmaxf(v, __shfl_xor(v, off, 64));
      acc[u] = v;
    }
    if (lane == 0) {
#pragma unroll
      for (int u = 0; u < 16; u += 4)
        *(float4*)(op + nc + u) = make_float4(acc[u], acc[u + 1], acc[u + 2], acc[u + 3]);
    }
  }
}

// write p2 into xin3 cols 256..258, zero-pad 259..271
__global__ void concat3_kernel(const float* __restrict__ c2, float* __restrict__ xin3) {
  int row = blockIdx.x * 256 + threadIdx.x;
  if (row < NBATCH * 512) {
    float* o = xin3 + (size_t)row * 272 + 256;
    const float* c = c2 + (size_t)row * 3;
    o[0] = c[0]; o[1] = c[1]; o[2] = c[2];
#pragma unroll
    for (int i = 3; i < 16; i++) o[i] = 0.f;
  }
}

// ---------------------------------------------------------------------------
// Tiled fp32 GEMM, 64x64 block tile, 256 threads (4x4 per thread), K-step 16.
// ---------------------------------------------------------------------------
template<int K, int KP, int N, int AST, bool RELU>
__global__ __launch_bounds__(256) void gemm64(const float* __restrict__ A,
    const float* __restrict__ W, const float* __restrict__ bias, float* __restrict__ C) {
  constexpr int NT = N / 64;
  const int bid = blockIdx.x, tid = threadIdx.x;
  const int tm = bid / NT, tn = bid % NT;
  __shared__ __align__(16) float As[16][68];
  __shared__ __align__(16) float Ws[16][68];
  const int arow = tid >> 2, acol = (tid & 3) << 2;
  const int wrow = tid >> 4, wcol = (tid & 15) << 2;
  const int ty = tid >> 4, tx = tid & 15;
  const float* Ap = A + (size_t)(tm * 64 + arow) * AST + acol;
  const float* Wp = W + (size_t)tn * 64 + wcol;
  float acc[4][4] = {};
  for (int k0 = 0; k0 < KP; k0 += 16) {
    float4 av = *(const float4*)(Ap + k0);
    As[acol + 0][arow] = av.x; As[acol + 1][arow] = av.y;
    As[acol + 2][arow] = av.z; As[acol + 3][arow] = av.w;
    int krow = k0 + wrow;
    float4 wv = make_float4(0.f, 0.f, 0.f, 0.f);
    if (krow < K) wv = *(const float4*)(Wp + (size_t)krow * N);
    *(float4*)(&Ws[wrow][wcol]) = wv;
    __syncthreads();
#pragma unroll
    for (int kk = 0; kk < 16; kk++) {
      float4 a4 = *(const float4*)(&As[kk][ty << 2]);
      float4 b4 = *(const float4*)(&Ws[kk][tx << 2]);
      float aa[4] = {a4.x, a4.y, a4.z, a4.w};
      float bb[4] = {b4.x, b4.y, b4.z, b4.w};
#pragma unroll
      for (int mm = 0; mm < 4; mm++)
#pragma unroll
        for (int nn = 0; nn < 4; nn++) acc[mm][nn] = fmaf(aa[mm], bb[nn], acc[mm][nn]);
    }
    __syncthreads();
  }
  const int m0 = tm * 64 + (ty << 2), n0 = tn * 64 + (tx << 2);
#pragma unroll
  for (int mm = 0; mm < 4; mm++) {
    float4 o;
    o.x = acc[mm][0] + bias[n0 + 0];
    o.y = acc[mm][1] + bias[n0 + 1];
    o.z = acc[mm][2] + bias[n0 + 2];
    o.w = acc[mm][3] + bias[n0 + 3];
    if (RELU) { o.x = fmaxf(o.x, 0.f); o.y = fmaxf(o.y, 0.f);
                o.z = fmaxf(o.z, 0.f); o.w = fmaxf(o.w, 0.f); }
    *(float4*)(C + (size_t)(m0 + mm) * N + n0) = o;
  }
}

// global max over 512 points per batch: [8,512,1024] -> [8,1024]
__global__ void gmax_kernel(const float* __restrict__ h, float* __restrict__ g) {
  int n = blockIdx.x * 256 + threadIdx.x;          // 8192 outputs
  int b = n >> 10, col = n & 1023;
  const float* p = h + ((size_t)b * 512) * 1024 + col;
  float m = -__builtin_inff();
  for (int j = 0; j < 512; j++) m = fmaxf(m, p[(size_t)j * 1024]);
  g[n] = m;
}

// head MLP: 1024 ->512 relu ->256 relu ->40. One block per batch.
__global__ __launch_bounds__(256) void head_kernel(const float* __restrict__ g,
    const float* __restrict__ w1, const float* __restrict__ b1,
    const float* __restrict__ w2, const float* __restrict__ b2,
    const float* __restrict__ w3, const float* __restrict__ b3,
    float* __restrict__ out) {
  int b = blockIdx.x, t = threadIdx.x;
  __shared__ float s1[1024];
  __shared__ float s2[512];
  *(float4*)(s1 + t * 4) = *(const float4*)(g + (size_t)b * 1024 + t * 4);
  __syncthreads();
  {
    float a0 = b1[t], a1 = b1[t + 256];
    for (int i = 0; i < 1024; i++) {
      float v = s1[i];
      a0 = fmaf(v, w1[(size_t)i * 512 + t], a0);
      a1 = fmaf(v, w1[(size_t)i * 512 + t + 256], a1);
    }
    s2[t] = fmaxf(a0, 0.f); s2[t + 256] = fmaxf(a1, 0.f);
  }
  __syncthreads();
  {
    float a = b2[t];
    for (int i = 0; i < 512; i++) a = fmaf(s2[i], w2[(size_t)i * 256 + t], a);
    s1[t] = fmaxf(a, 0.f);
  }
  __syncthreads();
  if (t < 40) {
    float a = b3[t];
    for (int i = 0; i < 256; i++) a = fmaf(s1[i], w3[(size_t)i * 40 + t], a);
    out[(size_t)b * 40 + t] = a;
  }
}

// ===========================================================================
extern "C" void kernel_launch(void* const* d_in, const int* in_sizes, int n_in,
                              void* d_out, int out_size, void* d_ws, size_t ws_size,
                              hipStream_t stream) {
  const float* x   = (const float*)d_in[0];
  const float* pos = (const float*)d_in[1];
  const float* w11 = (const float*)d_in[2];  const float* b11 = (const float*)d_in[3];
  const float* w12 = (const float*)d_in[4];  const float* b12 = (const float*)d_in[5];
  const float* w21 = (const float*)d_in[6];  const float* b21 = (const float*)d_in[7];
  const float* w22 = (const float*)d_in[8];  const float* b22 = (const float*)d_in[9];
  const float* w31 = (const float*)d_in[10]; const float* b31 = (const float*)d_in[11];
  const float* w32 = (const float*)d_in[12]; const float* b32 = (const float*)d_in[13];
  const float* w33 = (const float*)d_in[14]; const float* b33 = (const float*)d_in[15];
  const float* hw1 = (const float*)d_in[16]; const float* hb1 = (const float*)d_in[17];
  const float* hw2 = (const float*)d_in[18]; const float* hb2 = (const float*)d_in[19];
  const float* hw3 = (const float*)d_in[20]; const float* hb3 = (const float*)d_in[21];
  float* out = (float*)d_out;

  // workspace layout (aliased by liveness); total ~41.7 MB
  char* wsb = (char*)d_ws;
  int*   idx1 = (int*)(wsb + 0);           // 64K
  int*   idx2 = (int*)(wsb + 65536);       // 16K
  int*   cnt1 = (int*)(wsb + 81920);       // 64K
  int*   cnt2 = (int*)(wsb + 147456);      // 16K
  float* c1   = (float*)(wsb + 163840);    // 192K  (= p1)
  float* c2   = (float*)(wsb + 360448);    // 48K   (= p2)
  float* g    = (float*)(wsb + 409600);    // 32K
  char* big = wsb + 524288;
  int*   nbr1 = (int*)(big + 0);           // 4M   } dead after sa1_pool
  float* q1   = (float*)(big + 4194304);   // 8M   } -> h3c aliases (16M)
  float* t1   = (float*)(big + 12582912);  // 4M   }
  float* h3c  = (float*)(big + 0);
  float* x1   = (float*)(big + 16777216);  // 8M   } dead after q2/sa2_pool
  int*   nbr2 = (int*)(big + 25165824);    // 1M   } -> h3b aliases (8M)
  float* h3b  = (float*)(big + 16777216);
  float* q2   = (float*)(big + 26214400);  // 8M   -> h3a aliases (4M)
  float* h3a  = (float*)(big + 26214400);
  float* t2   = (float*)(big + 34603008);  // 2M
  float* xin3 = (float*)(big + 36700160);  // 4.45M  [8*512, 272]

  const float RR1 = (float)(0.2 * 0.2);    // match python-traced f32 constants
  const float RR2 = (float)(0.4 * 0.4);

  // ---- SA1 ----
  fps_kernel<4096, 512, 2048><<<NBATCH, 512, 0, stream>>>(pos, idx1, c1);
  q1_kernel<<<8192, 256, 0, stream>>>(x, pos, w11, q1);
  t1_kernel<<<4096, 256, 0, stream>>>(c1, w11, b11, t1);
  ballquery_kernel<4096, 2048><<<4096, 256, 0, stream>>>(pos, c1, RR1, nbr1, cnt1);
  sa_pool<64, 128, 128, 4096, 2048><<<4096, 256, 0, stream>>>(q1, t1, nbr1, cnt1, w12, b12, x1);
  // ---- SA2 ----
  fps_kernel<2048, 512, 512><<<NBATCH, 512, 0, stream>>>(c1, idx2, c2);
  q2_kernel<<<4096, 256, 0, stream>>>(x1, c1, w21, q2);
  t2_kernel<<<1024, 256, 0, stream>>>(c2, w21, b21, t2);
  ballquery_kernel<2048, 512><<<1024, 256, 0, stream>>>(c1, c2, RR2, nbr2, cnt2);
  sa_pool<128, 256, 272, 2048, 512><<<1024, 256, 0, stream>>>(q2, t2, nbr2, cnt2, w22, b22, xin3);
  // ---- global SA ----
  concat3_kernel<<<16, 256, 0, stream>>>(c2, xin3);
  gemm64<259, 272, 256, 272, true ><<<256,  256, 0, stream>>>(xin3, w31, b31, h3a);
  gemm64<256, 256, 512, 256, true ><<<512,  256, 0, stream>>>(h3a,  w32, b32, h3b);
  gemm64<512, 512, 1024, 512, false><<<1024, 256, 0, stream>>>(h3b, w33, b33, h3c);
  gmax_kernel<<<32, 256, 0, stream>>>(h3c, g);
  // ---- head ----
  head_kernel<<<NBATCH, 256, 0, stream>>>(g, hw1, hb1, hw2, hb2, hw3, hb3, out);

  (void)in_sizes; (void)n_in; (void)out_size; (void)ws_size;
}

// Round 7
// 3534.827 us; speedup vs baseline: 1.2912x; 1.2912x over previous
//
#include <hip/hip_runtime.h>

// ============================================================================
// PointNet++ (8 batches, N=4096) forward on MI355X — full pipeline, fp32.
// Round 7: FPS back to round-4 scalar structure (no spill) with LDS result
// accumulation (no vmcnt drain at the per-step barrier), plus dependency-
// graph kernel fusion so fps no longer serializes the whole GPU:
//   fuse1 = fps1 || q1        fuse2 = fps2 || ballquery1 || t1
//   fuse3 = sa_pool1 || ballquery2 || t2 || concat3
// ============================================================================

constexpr int NBATCH = 8;

// ---- DPP wave64 reduction helpers -----------------------------------------
template<int CTRL>
__device__ __forceinline__ float dpp_max_step(float v) {
  int o = __builtin_amdgcn_update_dpp(__float_as_int(v), __float_as_int(v),
                                      CTRL, 0xf, 0xf, false);  // invalid -> old(=v)
  return fmaxf(v, __int_as_float(o));
}
__device__ __forceinline__ float wave_max_bcast(float v) {
  v = dpp_max_step<0x111>(v);  // row_shr:1
  v = dpp_max_step<0x112>(v);  // row_shr:2
  v = dpp_max_step<0x114>(v);  // row_shr:4
  v = dpp_max_step<0x118>(v);  // row_shr:8
  v = dpp_max_step<0x142>(v);  // row_bcast:15
  v = dpp_max_step<0x143>(v);  // row_bcast:31
  return __int_as_float(__builtin_amdgcn_readlane(__float_as_int(v), 63));
}
template<int CTRL>
__device__ __forceinline__ int dpp_add_step(int v) {
  int o = __builtin_amdgcn_update_dpp(0, v, CTRL, 0xf, 0xf, true);  // invalid -> 0
  return v + o;
}
__device__ __forceinline__ int wave_sum_bcast(int v) {
  v = dpp_add_step<0x111>(v);
  v = dpp_add_step<0x112>(v);
  v = dpp_add_step<0x114>(v);
  v = dpp_add_step<0x118>(v);
  v = dpp_add_step<0x142>(v);
  v = dpp_add_step<0x143>(v);
  return __builtin_amdgcn_readlane(v, 63);
}

// ---------------------------------------------------------------------------
// FPS body (round-4 structure): scalar PT points/thread in registers,
// positions also in LDS for center lookup. Per step: dist+min update,
// per-lane argmax, DPP wave max, ballot lowest-lane index, packed u64 key
// per wave -> LDS, ONE barrier, NW-way merge. Selected indices accumulate
// in LDS (sidx); centers gathered from LDS at the end. No global traffic
// inside the barrier loop -> barrier drains lgkmcnt only, not vmcnt.
// ---------------------------------------------------------------------------
template<int NPTS, int NTH, int NSAMP>
__device__ void fps_body(const float* __restrict__ p, float* __restrict__ cb) {
#pragma clang fp contract(off)
  constexpr int PT = NPTS / NTH;
  constexpr int NW = NTH / 64;
  __shared__ float lx[NPTS], ly[NPTS], lz[NPTS];
  __shared__ unsigned long long wkey[2][NW];
  __shared__ int sidx[NSAMP];
  const int t = threadIdx.x, lane = t & 63, w = t >> 6;
  float px[PT], py[PT], pz[PT], md[PT];
#pragma unroll
  for (int i = 0; i < PT; i++) {
    int j = t * PT + i;
    px[i] = p[j * 3 + 0]; py[i] = p[j * 3 + 1]; pz[i] = p[j * 3 + 2];
    lx[j] = px[i]; ly[j] = py[i]; lz[j] = pz[i];
    md[i] = __builtin_inff();
  }
  __syncthreads();
  int cur = 0;
  for (int s = 0;; ++s) {
    float cx = lx[cur], cy = ly[cur], cz = lz[cur];
    if (t == 0) sidx[s] = cur;
    if (s == NSAMP - 1) break;
    float bv = -__builtin_inff(); int bi = 0;
#pragma unroll
    for (int i = 0; i < PT; i++) {
      float dx = px[i] - cx, dy = py[i] - cy, dz = pz[i] - cz;
      float d = (dx * dx + dy * dy) + dz * dz;   // contract off: match XLA order
      float m = fminf(md[i], d); md[i] = m;
      if (m > bv) { bv = m; bi = i; }            // strict > : first-index ties
    }
    float wmax = wave_max_bcast(bv);
    unsigned long long ball = __ballot(bv == wmax);
    int fl = __ffsll((long long)ball) - 1;       // lowest lane = lowest index
    int ib = __builtin_amdgcn_readlane(bi, fl);
    int gidx = ((w << 6) + fl) * PT + ib;
    if (lane == 0)
      wkey[s & 1][w] = (((unsigned long long)(unsigned)__float_as_int(wmax)) << 32)
                       | (unsigned)(~gidx);
    __syncthreads();
    unsigned long long best = wkey[s & 1][0];
#pragma unroll
    for (int q = 1; q < NW; q++) {
      unsigned long long k2 = wkey[s & 1][q];
      if (k2 > best) best = k2;                  // max d-bits, ties -> min gidx
    }
    cur = (int)(~(unsigned)best);
  }
  __syncthreads();
  // coalesced-ish dump: gather centers from LDS position arrays
  for (int i = t; i < NSAMP; i += NTH) {
    int id = sidx[i];
    cb[i * 3 + 0] = lx[id]; cb[i * 3 + 1] = ly[id]; cb[i * 3 + 2] = lz[id];
  }
}

// ---------------------------------------------------------------------------
// Ball query + exact 64 nearest within radius (one wave per center).
// ---------------------------------------------------------------------------
template<int NPTS, int SPB>
__device__ void ballquery_body(int bb, const float* __restrict__ pts,
    const float* __restrict__ ctr, float rr,
    int* __restrict__ nbr, int* __restrict__ cnt_out) {
#pragma clang fp contract(off)
  const int gw = (bb << 2) + (threadIdx.x >> 6);
  const int lane = threadIdx.x & 63;
  const int b = gw / SPB;
  __shared__ unsigned long long list_[4][1024];
  unsigned long long* list = list_[threadIdx.x >> 6];
  const float* p = pts + (size_t)b * NPTS * 3;
  const float* c = ctr + (size_t)gw * 3;
  const float cx = c[0], cy = c[1], cz = c[2];
  const unsigned long long lmask = (1ull << lane) - 1ull;
  int cnt = 0;
  for (int j0 = 0; j0 < NPTS; j0 += 64) {
    int j = j0 + lane;
    float dx = p[j * 3 + 0] - cx, dy = p[j * 3 + 1] - cy, dz = p[j * 3 + 2] - cz;
    float d = (dx * dx + dy * dy) + dz * dz;
    bool in = (d <= rr);
    unsigned long long bal = __ballot(in);
    int pos = cnt + __popcll(bal & lmask);
    if (in && pos < 1024)
      list[pos] = (((unsigned long long)__float_as_uint(d)) << 32) | (unsigned)j;
    cnt += __popcll(bal);
  }
  if (cnt > 1024) cnt = 1024;
  __syncthreads();
  int* nbrp = nbr + (size_t)gw * 64;
  const int nr = (cnt + 63) >> 6;
  unsigned long long key[16];
#pragma unroll
  for (int r = 0; r < 16; r++) {
    int slot = r * 64 + lane;
    key[r] = (r < nr && slot < cnt) ? list[slot] : ~0ull;
  }
  if (cnt <= 64) {
    nbrp[lane] = (lane < cnt) ? (int)(unsigned)key[0] : 0;
    if (lane == 0) cnt_out[gw] = cnt;
    return;
  }
  // radix select on d2 bits (d2 < 2.0 -> bits 31:30 are 0)
  unsigned pref = 0; int cbase = 0;
  for (int bit = 29; bit >= 0; --bit) {
    int cc = 0;
#pragma unroll
    for (int r = 0; r < 16; r++) if (r < nr) {
      unsigned db = (unsigned)(key[r] >> 32);
      cc += ((db >> bit) == (pref >> bit)) ? 1 : 0;
    }
    cc = wave_sum_bcast(cc);
    if (cbase + cc < 64) { cbase += cc; pref |= (1u << bit); }
  }
  int base = 0;
#pragma unroll
  for (int r = 0; r < 16; r++) if (r < nr) {
    unsigned db = (unsigned)(key[r] >> 32);
    bool sel = db < pref;
    unsigned long long m = __ballot(sel);
    if (sel) nbrp[base + __popcll(m & lmask)] = (int)(unsigned)key[r];
    base += __popcll(m);
  }
  int need = 64 - base;
  for (int t2 = 0; t2 < need; ++t2) {
    unsigned besti = 0xffffffffu;
#pragma unroll
    for (int r = 0; r < 16; r++) if (r < nr) {
      if ((unsigned)(key[r] >> 32) == pref) {
        unsigned v = (unsigned)key[r];
        besti = v < besti ? v : besti;
      }
    }
#pragma unroll
    for (int off = 32; off; off >>= 1) {
      unsigned o = __shfl_xor(besti, off, 64);
      besti = o < besti ? o : besti;
    }
    unsigned long long wk = (((unsigned long long)pref) << 32) | besti;
#pragma unroll
    for (int r = 0; r < 16; r++) if (r < nr && key[r] == wk) key[r] = ~0ull;
    if (lane == 0) nbrp[base + t2] = (int)besti;
  }
  if (lane == 0) cnt_out[gw] = 64;
}

// ---- SA layer-1 split bodies ----------------------------------------------
__device__ void q1_body(int bb, const float* __restrict__ x,
    const float* __restrict__ pos, const float* __restrict__ w, float* __restrict__ q) {
  int gw = bb * 8 + (threadIdx.x >> 6), lane = threadIdx.x & 63;  // 512-thr blocks
  const float* xr = x + (size_t)gw * 3; const float* pr = pos + (size_t)gw * 3;
  float a = 0.f;
#pragma unroll
  for (int m = 0; m < 3; m++) a = fmaf(xr[m], w[m * 64 + lane], a);
#pragma unroll
  for (int m = 0; m < 3; m++) a = fmaf(pr[m], w[(3 + m) * 64 + lane], a);
  q[(size_t)gw * 64 + lane] = a;
}

__device__ void t1_body(int bb, const float* __restrict__ c1,
    const float* __restrict__ w, const float* __restrict__ b1, float* __restrict__ t) {
  int gw = (bb << 2) + (threadIdx.x >> 6), lane = threadIdx.x & 63;
  const float* cr = c1 + (size_t)gw * 3;
  float a = b1[lane];
#pragma unroll
  for (int m = 0; m < 3; m++) a = fmaf(-cr[m], w[(3 + m) * 64 + lane], a);
  t[(size_t)gw * 64 + lane] = a;
}

__device__ void t2_body(int bb, const float* __restrict__ c2,
    const float* __restrict__ w, const float* __restrict__ b1, float* __restrict__ t) {
  int gw = (bb << 2) + (threadIdx.x >> 6), lane = threadIdx.x & 63;
  const float* cr = c2 + (size_t)gw * 3;
  float a0 = b1[lane], a1 = b1[64 + lane];
#pragma unroll
  for (int m = 0; m < 3; m++) {
    a0 = fmaf(-cr[m], w[(128 + m) * 128 + lane], a0);
    a1 = fmaf(-cr[m], w[(128 + m) * 128 + 64 + lane], a1);
  }
  t[(size_t)gw * 128 + lane] = a0;
  t[(size_t)gw * 128 + 64 + lane] = a1;
}

__device__ void concat3_body(int bb, const float* __restrict__ c2, float* __restrict__ xin3) {
  int row = bb * 256 + threadIdx.x;
  if (row < NBATCH * 512) {
    float* o = xin3 + (size_t)row * 272 + 256;
    const float* c = c2 + (size_t)row * 3;
    o[0] = c[0]; o[1] = c[1]; o[2] = c[2];
#pragma unroll
    for (int i = 3; i < 16; i++) o[i] = 0.f;
  }
}

// ---------------------------------------------------------------------------
// Per-center: h1[k] = relu(q[nbr_k] + t_s); h2 = h1 @ W2 + b2; out = max_k h2.
// ---------------------------------------------------------------------------
template<int CIN, int COUT, int OSTR, int NPB, int SPB>
__device__ void sa_pool_body(int bb, const float* __restrict__ q,
    const float* __restrict__ t, const int* __restrict__ nbr, const int* __restrict__ cnt,
    const float* __restrict__ w2, const float* __restrict__ b2, float* __restrict__ out) {
  int gw = (bb << 2) + (threadIdx.x >> 6), lane = threadIdx.x & 63;
  int b = gw / SPB;
  int nk = nbr[(size_t)gw * 64 + lane];
  int c = cnt[gw];
  const float* qr = q + ((size_t)b * NPB + nk) * CIN;
  const float* tr = t + (size_t)gw * CIN;
  float h[CIN];
#pragma unroll
  for (int i = 0; i < CIN; i += 4) {
    float4 v = *(const float4*)(qr + i);
    h[i]     = fmaxf(v.x + tr[i], 0.f);
    h[i + 1] = fmaxf(v.y + tr[i + 1], 0.f);
    h[i + 2] = fmaxf(v.z + tr[i + 2], 0.f);
    h[i + 3] = fmaxf(v.w + tr[i + 3], 0.f);
  }
  bool valid = lane < c;
  float* op = out + (size_t)gw * OSTR;
#pragma unroll 1
  for (int nc = 0; nc < COUT; nc += 16) {
    float acc[16];
#pragma unroll
    for (int u = 0; u < 16; u++) acc[u] = b2[nc + u];
#pragma unroll
    for (int i = 0; i < CIN; i++) {
      const float* wr = w2 + (size_t)i * COUT + nc;
#pragma unroll
      for (int u = 0; u < 16; u++) acc[u] = fmaf(h[i], wr[u], acc[u]);
    }
#pragma unroll
    for (int u = 0; u < 16; u++) {
      float v = valid ? acc[u] : -__builtin_inff();
#pragma unroll
      for (int off = 32; off; off >>= 1) v = fmaxf(v, __shfl_xor(v, off, 64));
      acc[u] = v;
    }
    if (lane == 0) {
#pragma unroll
      for (int u = 0; u < 16; u += 4)
        *(float4*)(op + nc + u) = make_float4(acc[u], acc[u + 1], acc[u + 2], acc[u + 3]);
    }
  }
}

// ---- fused kernels ---------------------------------------------------------
__global__ __launch_bounds__(512) void fuse1_kernel(const float* __restrict__ pos,
    const float* __restrict__ x, const float* __restrict__ w11,
    float* __restrict__ c1, float* __restrict__ q1) {
  int bid = blockIdx.x;
  if (bid < 8)
    fps_body<4096, 512, 2048>(pos + (size_t)bid * 4096 * 3, c1 + (size_t)bid * 2048 * 3);
  else
    q1_body(bid - 8, x, pos, w11, q1);
}

__global__ __launch_bounds__(256) void fuse2_kernel(const float* __restrict__ pos,
    const float* __restrict__ c1, const float* __restrict__ w11, const float* __restrict__ b11,
    float* __restrict__ c2, int* __restrict__ nbr1, int* __restrict__ cnt1,
    float* __restrict__ t1buf, float rr1) {
  int bid = blockIdx.x;
  if (bid < 8)
    fps_body<2048, 256, 512>(c1 + (size_t)bid * 2048 * 3, c2 + (size_t)bid * 512 * 3);
  else if (bid < 8 + 4096)
    ballquery_body<4096, 2048>(bid - 8, pos, c1, rr1, nbr1, cnt1);
  else
    t1_body(bid - (8 + 4096), c1, w11, b11, t1buf);
}

__global__ __launch_bounds__(256) void fuse3_kernel(const float* __restrict__ q1buf,
    const float* __restrict__ t1buf, const int* __restrict__ nbr1, const int* __restrict__ cnt1,
    const float* __restrict__ w12, const float* __restrict__ b12, float* __restrict__ x1,
    const float* __restrict__ c1, const float* __restrict__ c2, float rr2,
    int* __restrict__ nbr2, int* __restrict__ cnt2,
    const float* __restrict__ w21, const float* __restrict__ b21, float* __restrict__ t2buf,
    float* __restrict__ xin3) {
  int bid = blockIdx.x;
  if (bid < 4096)
    sa_pool_body<64, 128, 128, 4096, 2048>(bid, q1buf, t1buf, nbr1, cnt1, w12, b12, x1);
  else if (bid < 4096 + 1024)
    ballquery_body<2048, 512>(bid - 4096, c1, c2, rr2, nbr2, cnt2);
  else if (bid < 4096 + 1024 + 1024)
    t2_body(bid - (4096 + 1024), c2, w21, b21, t2buf);
  else
    concat3_body(bid - (4096 + 1024 + 1024), c2, xin3);
}

// SA2 layer-1 q: q2[j] = [x1_j,p1_j] @ W1 (131->128)
__global__ __launch_bounds__(256) void q2_kernel(const float* __restrict__ x1,
    const float* __restrict__ p1, const float* __restrict__ w, float* __restrict__ q2) {
  int gw = (blockIdx.x << 2) + (threadIdx.x >> 6), lane = threadIdx.x & 63;
  const float* xr = x1 + (size_t)gw * 128; const float* pr = p1 + (size_t)gw * 3;
  float a0 = 0.f, a1 = 0.f;
#pragma unroll 8
  for (int m = 0; m < 128; m++) {
    float v = xr[m];
    a0 = fmaf(v, w[m * 128 + lane], a0);
    a1 = fmaf(v, w[m * 128 + 64 + lane], a1);
  }
#pragma unroll
  for (int m = 0; m < 3; m++) {
    float v = pr[m];
    a0 = fmaf(v, w[(128 + m) * 128 + lane], a0);
    a1 = fmaf(v, w[(128 + m) * 128 + 64 + lane], a1);
  }
  q2[(size_t)gw * 128 + lane] = a0;
  q2[(size_t)gw * 128 + 64 + lane] = a1;
}

__global__ __launch_bounds__(256) void sa_pool2_kernel(const float* __restrict__ q,
    const float* __restrict__ t, const int* __restrict__ nbr, const int* __restrict__ cnt,
    const float* __restrict__ w2, const float* __restrict__ b2, float* __restrict__ out) {
  sa_pool_body<128, 256, 272, 2048, 512>(blockIdx.x, q, t, nbr, cnt, w2, b2, out);
}

// ---------------------------------------------------------------------------
// Tiled fp32 GEMM, 64x64 block tile, 256 threads (4x4 per thread), K-step 16.
// ---------------------------------------------------------------------------
template<int K, int KP, int N, int AST, bool RELU>
__global__ __launch_bounds__(256) void gemm64(const float* __restrict__ A,
    const float* __restrict__ W, const float* __restrict__ bias, float* __restrict__ C) {
  constexpr int NT = N / 64;
  const int bid = blockIdx.x, tid = threadIdx.x;
  const int tm = bid / NT, tn = bid % NT;
  __shared__ __align__(16) float As[16][68];
  __shared__ __align__(16) float Ws[16][68];
  const int arow = tid >> 2, acol = (tid & 3) << 2;
  const int wrow = tid >> 4, wcol = (tid & 15) << 2;
  const int ty = tid >> 4, tx = tid & 15;
  const float* Ap = A + (size_t)(tm * 64 + arow) * AST + acol;
  const float* Wp = W + (size_t)tn * 64 + wcol;
  float acc[4][4] = {};
  for (int k0 = 0; k0 < KP; k0 += 16) {
    float4 av = *(const float4*)(Ap + k0);
    As[acol + 0][arow] = av.x; As[acol + 1][arow] = av.y;
    As[acol + 2][arow] = av.z; As[acol + 3][arow] = av.w;
    int krow = k0 + wrow;
    float4 wv = make_float4(0.f, 0.f, 0.f, 0.f);
    if (krow < K) wv = *(const float4*)(Wp + (size_t)krow * N);
    *(float4*)(&Ws[wrow][wcol]) = wv;
    __syncthreads();
#pragma unroll
    for (int kk = 0; kk < 16; kk++) {
      float4 a4 = *(const float4*)(&As[kk][ty << 2]);
      float4 b4 = *(const float4*)(&Ws[kk][tx << 2]);
      float aa[4] = {a4.x, a4.y, a4.z, a4.w};
      float bb[4] = {b4.x, b4.y, b4.z, b4.w};
#pragma unroll
      for (int mm = 0; mm < 4; mm++)
#pragma unroll
        for (int nn = 0; nn < 4; nn++) acc[mm][nn] = fmaf(aa[mm], bb[nn], acc[mm][nn]);
    }
    __syncthreads();
  }
  const int m0 = tm * 64 + (ty << 2), n0 = tn * 64 + (tx << 2);
#pragma unroll
  for (int mm = 0; mm < 4; mm++) {
    float4 o;
    o.x = acc[mm][0] + bias[n0 + 0];
    o.y = acc[mm][1] + bias[n0 + 1];
    o.z = acc[mm][2] + bias[n0 + 2];
    o.w = acc[mm][3] + bias[n0 + 3];
    if (RELU) { o.x = fmaxf(o.x, 0.f); o.y = fmaxf(o.y, 0.f);
                o.z = fmaxf(o.z, 0.f); o.w = fmaxf(o.w, 0.f); }
    *(float4*)(C + (size_t)(m0 + mm) * N + n0) = o;
  }
}

// global max over 512 points per batch: [8,512,1024] -> [8,1024]
__global__ void gmax_kernel(const float* __restrict__ h, float* __restrict__ g) {
  int n = blockIdx.x * 256 + threadIdx.x;          // 8192 outputs
  int b = n >> 10, col = n & 1023;
  const float* p = h + ((size_t)b * 512) * 1024 + col;
  float m = -__builtin_inff();
  for (int j = 0; j < 512; j++) m = fmaxf(m, p[(size_t)j * 1024]);
  g[n] = m;
}

// head MLP: 1024 ->512 relu ->256 relu ->40. One block per batch.
__global__ __launch_bounds__(256) void head_kernel(const float* __restrict__ g,
    const float* __restrict__ w1, const float* __restrict__ b1,
    const float* __restrict__ w2, const float* __restrict__ b2,
    const float* __restrict__ w3, const float* __restrict__ b3,
    float* __restrict__ out) {
  int b = blockIdx.x, t = threadIdx.x;
  __shared__ float s1[1024];
  __shared__ float s2[512];
  *(float4*)(s1 + t * 4) = *(const float4*)(g + (size_t)b * 1024 + t * 4);
  __syncthreads();
  {
    float a0 = b1[t], a1 = b1[t + 256];
    for (int i = 0; i < 1024; i++) {
      float v = s1[i];
      a0 = fmaf(v, w1[(size_t)i * 512 + t], a0);
      a1 = fmaf(v, w1[(size_t)i * 512 + t + 256], a1);
    }
    s2[t] = fmaxf(a0, 0.f); s2[t + 256] = fmaxf(a1, 0.f);
  }
  __syncthreads();
  {
    float a = b2[t];
    for (int i = 0; i < 512; i++) a = fmaf(s2[i], w2[(size_t)i * 256 + t], a);
    s1[t] = fmaxf(a, 0.f);
  }
  __syncthreads();
  if (t < 40) {
    float a = b3[t];
    for (int i = 0; i < 256; i++) a = fmaf(s1[i], w3[(size_t)i * 40 + t], a);
    out[(size_t)b * 40 + t] = a;
  }
}

// ===========================================================================
extern "C" void kernel_launch(void* const* d_in, const int* in_sizes, int n_in,
                              void* d_out, int out_size, void* d_ws, size_t ws_size,
                              hipStream_t stream) {
  const float* x   = (const float*)d_in[0];
  const float* pos = (const float*)d_in[1];
  const float* w11 = (const float*)d_in[2];  const float* b11 = (const float*)d_in[3];
  const float* w12 = (const float*)d_in[4];  const float* b12 = (const float*)d_in[5];
  const float* w21 = (const float*)d_in[6];  const float* b21 = (const float*)d_in[7];
  const float* w22 = (const float*)d_in[8];  const float* b22 = (const float*)d_in[9];
  const float* w31 = (const float*)d_in[10]; const float* b31 = (const float*)d_in[11];
  const float* w32 = (const float*)d_in[12]; const float* b32 = (const float*)d_in[13];
  const float* w33 = (const float*)d_in[14]; const float* b33 = (const float*)d_in[15];
  const float* hw1 = (const float*)d_in[16]; const float* hb1 = (const float*)d_in[17];
  const float* hw2 = (const float*)d_in[18]; const float* hb2 = (const float*)d_in[19];
  const float* hw3 = (const float*)d_in[20]; const float* hb3 = (const float*)d_in[21];
  float* out = (float*)d_out;

  // workspace layout (aliased by liveness); total ~41.7 MB
  char* wsb = (char*)d_ws;
  int*   cnt1 = (int*)(wsb + 81920);       // 64K
  int*   cnt2 = (int*)(wsb + 147456);      // 16K
  float* c1   = (float*)(wsb + 163840);    // 192K  (= p1)
  float* c2   = (float*)(wsb + 360448);    // 48K   (= p2)
  float* g    = (float*)(wsb + 409600);    // 32K
  char* big = wsb + 524288;
  int*   nbr1 = (int*)(big + 0);           // 4M   } dead after sa_pool1
  float* q1   = (float*)(big + 4194304);   // 8M   } -> h3c aliases (16M)
  float* t1   = (float*)(big + 12582912);  // 4M   }
  float* h3c  = (float*)(big + 0);
  float* x1   = (float*)(big + 16777216);  // 8M   } dead after q2/sa_pool2
  int*   nbr2 = (int*)(big + 25165824);    // 1M   } -> h3b aliases (8M)
  float* h3b  = (float*)(big + 16777216);
  float* q2   = (float*)(big + 26214400);  // 8M   -> h3a aliases (4M)
  float* h3a  = (float*)(big + 26214400);
  float* t2   = (float*)(big + 34603008);  // 2M
  float* xin3 = (float*)(big + 36700160);  // 4.45M  [8*512, 272]

  const float RR1 = (float)(0.2 * 0.2);    // match python-traced f32 constants
  const float RR2 = (float)(0.4 * 0.4);

  // ---- stage 1: fps1 || q1 ----
  fuse1_kernel<<<8 + 4096, 512, 0, stream>>>(pos, x, w11, c1, q1);
  // ---- stage 2: fps2 || ballquery1 || t1 ----
  fuse2_kernel<<<8 + 4096 + 4096, 256, 0, stream>>>(pos, c1, w11, b11,
                                                    c2, nbr1, cnt1, t1, RR1);
  // ---- stage 3: sa_pool1 || ballquery2 || t2 || concat3 ----
  fuse3_kernel<<<4096 + 1024 + 1024 + 16, 256, 0, stream>>>(q1, t1, nbr1, cnt1,
      w12, b12, x1, c1, c2, RR2, nbr2, cnt2, w21, b21, t2, xin3);
  // ---- stage 4+: SA2 finish, global SA, head ----
  q2_kernel<<<4096, 256, 0, stream>>>(x1, c1, w21, q2);
  sa_pool2_kernel<<<1024, 256, 0, stream>>>(q2, t2, nbr2, cnt2, w22, b22, xin3);
  gemm64<259, 272, 256, 272, true ><<<256,  256, 0, stream>>>(xin3, w31, b31, h3a);
  gemm64<256, 256, 512, 256, true ><<<512,  256, 0, stream>>>(h3a,  w32, b32, h3b);
  gemm64<512, 512, 1024, 512, false><<<1024, 256, 0, stream>>>(h3b, w33, b33, h3c);
  gmax_kernel<<<32, 256, 0, stream>>>(h3c, g);
  head_kernel<<<NBATCH, 256, 0, stream>>>(g, hw1, hb1, hw2, hb2, hw3, hb3, out);

  (void)in_sizes; (void)n_in; (void)out_size; (void)ws_size;
}